// Round 1
// baseline (67.634 us; speedup 1.0000x reference)
//
#include <hip/hip_runtime.h>
#include <hip/hip_bf16.h>

#define H 1024
#define V 50257
#define L 100
#define NPART 1024   // k6 grid size == number of (m,s) partials

// ---------- helpers ----------

__device__ __forceinline__ float block_reduce_sum_256(float v, float* sbuf4) {
    #pragma unroll
    for (int off = 32; off > 0; off >>= 1)
        v += __shfl_down(v, off, 64);
    int lane = threadIdx.x & 63;
    int wid  = threadIdx.x >> 6;
    __syncthreads();                 // protect sbuf4 reuse across calls
    if (lane == 0) sbuf4[wid] = v;
    __syncthreads();
    return sbuf4[0] + sbuf4[1] + sbuf4[2] + sbuf4[3];  // broadcast to all threads
}

// ---------- k1: attn logits (blocks 0..99) + gh = h0 @ w_hh.T + b_hh (blocks 100..867) ----------

__global__ void k1_logits_gh(const int* token, const float* hidden, const float* embedding,
                             const float* attn_w, const float* attn_b,
                             const float* w_hh, const float* b_hh,
                             float* ws_log, float* ws_gh) {
    __shared__ float sbuf[4];
    int b = blockIdx.x;
    if (b < L) {
        int tok = token[0];
        const float* emb = embedding + (size_t)tok * H;
        const float* wrow = attn_w + (size_t)b * (2 * H);
        float acc = 0.f;
        for (int k = threadIdx.x; k < 2 * H; k += 256) {
            float inv = (k < H) ? emb[k] : hidden[k - H];
            acc += inv * wrow[k];
        }
        float s = block_reduce_sum_256(acc, sbuf);
        if (threadIdx.x == 0) ws_log[b] = s + attn_b[b];
    } else {
        int rb = b - L;                       // 0..767, 4 rows each
        float4 hv = ((const float4*)hidden)[threadIdx.x];
        #pragma unroll
        for (int i = 0; i < 4; i++) {
            int r = rb * 4 + i;
            const float4* wr = (const float4*)(w_hh + (size_t)r * H);
            float4 w = wr[threadIdx.x];
            float acc = w.x * hv.x + w.y * hv.y + w.z * hv.z + w.w * hv.w;
            float s = block_reduce_sum_256(acc, sbuf);
            if (threadIdx.x == 0) ws_gh[r] = s + b_hh[r];
        }
    }
}

// ---------- k2: softmax over L + attn_applied + attn_weights output ----------

__global__ void k2_softmax_apply(const float* ws_log, const float* enc,
                                 float* ws_app, float* out_attnw) {
    __shared__ float wsm[L];
    if (threadIdx.x < L) wsm[threadIdx.x] = ws_log[threadIdx.x];
    __syncthreads();
    float m = -1e30f;
    for (int l = 0; l < L; l++) m = fmaxf(m, wsm[l]);
    float s = 0.f;
    for (int l = 0; l < L; l++) s += expf(wsm[l] - m);
    __syncthreads();
    if (threadIdx.x < L) wsm[threadIdx.x] = expf(wsm[threadIdx.x] - m) / s;
    __syncthreads();
    int h = blockIdx.x * 256 + threadIdx.x;       // grid 4 -> covers H
    float acc = 0.f;
    for (int l = 0; l < L; l++) acc += wsm[l] * enc[l * H + h];
    ws_app[h] = acc;
    if (blockIdx.x == 0 && threadIdx.x < L) out_attnw[threadIdx.x] = wsm[threadIdx.x];
}

// ---------- k3: x = relu(concat(emb, applied) @ comb_w.T + comb_b) ----------

__global__ void k3_combine(const int* token, const float* embedding, const float* ws_app,
                           const float* comb_w, const float* comb_b, float* ws_x) {
    __shared__ float sbuf[4];
    int tok = token[0];
    const float* emb = embedding + (size_t)tok * H;
    float4 e = ((const float4*)emb)[threadIdx.x];
    float4 a = ((const float4*)ws_app)[threadIdx.x];
    for (int r = blockIdx.x; r < H; r += gridDim.x) {
        const float4* wr = (const float4*)(comb_w + (size_t)r * (2 * H));
        float4 w0 = wr[threadIdx.x];
        float4 w1 = wr[256 + threadIdx.x];
        float acc = w0.x * e.x + w0.y * e.y + w0.z * e.z + w0.w * e.w
                  + w1.x * a.x + w1.y * a.y + w1.z * a.z + w1.w * a.w;
        float s = block_reduce_sum_256(acc, sbuf);
        if (threadIdx.x == 0) ws_x[r] = fmaxf(s + comb_b[r], 0.0f);
    }
}

// ---------- k4: gi = x @ w_ih.T + b_ih ----------

__global__ void k4_gi(const float* ws_x, const float* w_ih, const float* b_ih, float* ws_gi) {
    __shared__ float sbuf[4];
    float4 xv = ((const float4*)ws_x)[threadIdx.x];
    for (int r = blockIdx.x; r < 3 * H; r += gridDim.x) {
        const float4* wr = (const float4*)(w_ih + (size_t)r * H);
        float4 w = wr[threadIdx.x];
        float acc = w.x * xv.x + w.y * xv.y + w.z * xv.z + w.w * xv.w;
        float s = block_reduce_sum_256(acc, sbuf);
        if (threadIdx.x == 0) ws_gi[r] = s + b_ih[r];
    }
}

// ---------- k5: GRU gates -> h_new ----------

__global__ void k5_gates(const float* ws_gi, const float* ws_gh, const float* hidden,
                         float* out_h, float* ws_hn) {
    int h = blockIdx.x * 256 + threadIdx.x;       // grid 4 -> covers H
    float ir = ws_gi[h], iz = ws_gi[H + h], in_ = ws_gi[2 * H + h];
    float hr = ws_gh[h], hz = ws_gh[H + h], hn = ws_gh[2 * H + h];
    float r = 1.f / (1.f + expf(-(ir + hr)));
    float z = 1.f / (1.f + expf(-(iz + hz)));
    float n = tanhf(in_ + r * hn);
    float h0 = hidden[h];
    float v = (1.f - z) * n + z * h0;
    out_h[h] = v;
    ws_hn[h] = v;      // 16B-aligned copy for k6's float4 reads
}

// ---------- k6: logits = h_new @ out_w.T + out_b (wave-per-row) + per-block (m,s) ----------

__global__ void k6_outproj(const float* hn, const float* out_w, const float* out_b,
                           float* out_logits, float* ws_pm, float* ws_ps) {
    __shared__ float sm[4], ss[4];
    int lane = threadIdx.x & 63;
    int wv   = threadIdx.x >> 6;
    const float4* h4 = (const float4*)hn;
    float4 h0 = h4[lane], h1 = h4[lane + 64], h2 = h4[lane + 128], h3 = h4[lane + 192];
    float m = -1e30f, s = 0.f;
    int wid = blockIdx.x * 4 + wv;                // 0..4095
    for (int r = wid; r < V; r += NPART * 4) {
        const float4* wr = (const float4*)(out_w + (size_t)r * H);
        float4 a = wr[lane], b = wr[lane + 64], c = wr[lane + 128], d = wr[lane + 192];
        float acc = a.x * h0.x + a.y * h0.y + a.z * h0.z + a.w * h0.w
                  + b.x * h1.x + b.y * h1.y + b.z * h1.z + b.w * h1.w
                  + c.x * h2.x + c.y * h2.y + c.z * h2.z + c.w * h2.w
                  + d.x * h3.x + d.y * h3.y + d.z * h3.z + d.w * h3.w;
        #pragma unroll
        for (int off = 32; off > 0; off >>= 1) acc += __shfl_down(acc, off, 64);
        if (lane == 0) {
            float lg = acc + out_b[r];
            out_logits[r] = lg;
            float nm = fmaxf(m, lg);
            s = s * expf(m - nm) + expf(lg - nm);
            m = nm;
        }
    }
    if (lane == 0) { sm[wv] = m; ss[wv] = s; }
    __syncthreads();
    if (threadIdx.x == 0) {
        m = sm[0]; s = ss[0];
        for (int i = 1; i < 4; i++) {
            float nm = fmaxf(m, sm[i]);
            s = s * expf(m - nm) + ss[i] * expf(sm[i] - nm);
            m = nm;
        }
        ws_pm[blockIdx.x] = m;
        ws_ps[blockIdx.x] = s;
    }
}

// ---------- k7: reduce partials (redundant per block) + in-place log_softmax finalize ----------

__global__ void k7_finalize(const float* ws_pm, const float* ws_ps, float* out) {
    __shared__ float sm[4], ss[4], fm, fs;
    int t = threadIdx.x;
    float m = -1e30f, s = 0.f;
    for (int i = t; i < NPART; i += 256) {
        float pm = ws_pm[i], ps = ws_ps[i];
        float nm = fmaxf(m, pm);
        s = s * expf(m - nm) + ps * expf(pm - nm);
        m = nm;
    }
    #pragma unroll
    for (int off = 32; off > 0; off >>= 1) {
        float om = __shfl_down(m, off, 64);
        float os = __shfl_down(s, off, 64);
        float nm = fmaxf(m, om);
        s = s * expf(m - nm) + os * expf(om - nm);
        m = nm;
    }
    int lane = t & 63, wv = t >> 6;
    if (lane == 0) { sm[wv] = m; ss[wv] = s; }
    __syncthreads();
    if (t == 0) {
        m = sm[0]; s = ss[0];
        for (int i = 1; i < 4; i++) {
            float nm = fmaxf(m, sm[i]);
            s = s * expf(m - nm) + ss[i] * expf(sm[i] - nm);
            m = nm;
        }
        fm = m; fs = logf(s);
    }
    __syncthreads();
    float M = fm, LS = fs;
    for (int v = blockIdx.x * 256 + t; v < V; v += gridDim.x * 256)
        out[v] = out[v] - M - LS;
}

// ---------- launch ----------

extern "C" void kernel_launch(void* const* d_in, const int* in_sizes, int n_in,
                              void* d_out, int out_size, void* d_ws, size_t ws_size,
                              hipStream_t stream) {
    const int*   token     = (const int*)d_in[0];
    const float* hidden    = (const float*)d_in[1];
    const float* enc       = (const float*)d_in[2];
    const float* embedding = (const float*)d_in[3];
    const float* attn_w    = (const float*)d_in[4];
    const float* attn_b    = (const float*)d_in[5];
    const float* comb_w    = (const float*)d_in[6];
    const float* comb_b    = (const float*)d_in[7];
    const float* w_ih      = (const float*)d_in[8];
    const float* w_hh      = (const float*)d_in[9];
    const float* b_ih      = (const float*)d_in[10];
    const float* b_hh      = (const float*)d_in[11];
    const float* out_w     = (const float*)d_in[12];
    const float* out_b     = (const float*)d_in[13];

    float* out = (float*)d_out;           // [0,V) log_softmax | [V,V+H) h_new | [V+H,V+H+L) attn_w
    float* ws  = (float*)d_ws;
    float* ws_log = ws;                   // 100
    float* ws_app = ws + 128;             // 1024
    float* ws_x   = ws + 1152;            // 1024
    float* ws_gi  = ws + 2176;            // 3072
    float* ws_gh  = ws + 5248;            // 3072
    float* ws_pm  = ws + 8320;            // 1024
    float* ws_ps  = ws + 9344;            // 1024
    float* ws_hn  = ws + 10368;           // 1024

    k1_logits_gh<<<dim3(L + 768), dim3(256), 0, stream>>>(token, hidden, embedding,
                                                          attn_w, attn_b, w_hh, b_hh,
                                                          ws_log, ws_gh);
    k2_softmax_apply<<<dim3(4), dim3(256), 0, stream>>>(ws_log, enc, ws_app, out + V + H);
    k3_combine<<<dim3(256), dim3(256), 0, stream>>>(token, embedding, ws_app,
                                                    comb_w, comb_b, ws_x);
    k4_gi<<<dim3(768), dim3(256), 0, stream>>>(ws_x, w_ih, b_ih, ws_gi);
    k5_gates<<<dim3(4), dim3(256), 0, stream>>>(ws_gi, ws_gh, hidden, out + V, ws_hn);
    k6_outproj<<<dim3(NPART), dim3(256), 0, stream>>>(ws_hn, out_w, out_b, out, ws_pm, ws_ps);
    k7_finalize<<<dim3(64), dim3(256), 0, stream>>>(ws_pm, ws_ps, out);
}